// Round 3
// baseline (132.004 us; speedup 1.0000x reference)
//
#include <hip/hip_runtime.h>

// StructuredStateSpace: h_t = A h_{t-1} + Bw x_t + Bb ; y_t = Cw h_t
// B=16, S=8192, D_IN=64, D_ST=128.  Output scale +-488, threshold 0.32
// => need ~6.6e-4 RELATIVE accuracy: every matrix/state is carried as an
// f16 hi+lo pair (21-bit effective), products keep 3 of 4 cross terms.
// Chunked scan, W=112 warm-up (64 cheap single-f16 + 48 full), L=32.
// Block = 2 waves (m-split); rho permutation makes the per-step state
// handoff a per-lane-slot LDS exchange (wave0 writes dwords {0,2},
// wave1 {1,3} of each lane's own next B-fragment).

#define SEQ   8192
#define DIN   64
#define LCH   32
#define NCH   (SEQ / LCH)        // 256
#define WFULL 48
#define WTOT  112

typedef _Float16 v8h __attribute__((ext_vector_type(8)));
typedef __fp16   v2h __attribute__((ext_vector_type(2)));
typedef float    v4f __attribute__((ext_vector_type(4)));

#define MFMA(a, b, c) __builtin_amdgcn_mfma_f32_16x16x32_f16((a), (b), (c), 0, 0, 0)
#define PKRTZ __builtin_amdgcn_cvt_pkrtz

// rho: logical state l = 32*kt + 8*q + e  ->  physical D-row p = 16*m + 4*q + r
// with m = kt + 4*(eh&1), r = 2*(eh>>1) + (e&1), eh = e>>1.
__device__ __forceinline__ int rho_inv(int p) {
  int m = p >> 4, q = (p >> 2) & 3, r = p & 3;
  int eh = ((r >> 1) << 1) | (m >> 2);
  int e  = (eh << 1) | (r & 1);
  return 32 * (m & 3) + 8 * q + e;
}

// ws (f16 units): Ah[0,16384) Al[16384,32768) Bwh[32768,40960) Bwl[40960,49152)
// Cwh[49152,57344) Cwl[57344,65536) ; then f32 Bb[128].  Total 131584 B.
__global__ void prep_kernel(const float* __restrict__ A, const float* __restrict__ Bw,
                            const float* __restrict__ Bb, const float* __restrict__ Cw,
                            _Float16* __restrict__ W, float* __restrict__ Bbs) {
  int idx = blockIdx.x * 256 + threadIdx.x;
  float v; int off_hi, off_lo;
  if (idx < 16384) {                       // A: 128x128, rho rows
    int p = idx >> 7, j = idx & 127;
    v = A[rho_inv(p) * 128 + j]; off_hi = idx; off_lo = idx + 16384;
  } else if (idx < 24576) {                // Bw: 128x64, rho rows
    int i2 = idx - 16384; int p = i2 >> 6, j = i2 & 63;
    v = Bw[rho_inv(p) * 64 + j]; off_hi = 32768 + i2; off_lo = 40960 + i2;
  } else if (idx < 32768) {                // Cw: 64x128, plain
    int i2 = idx - 24576;
    v = Cw[i2]; off_hi = 49152 + i2; off_lo = 57344 + i2;
  } else if (idx < 32896) {                // Bb f32, rho
    Bbs[idx - 32768] = Bb[rho_inv(idx - 32768)]; return;
  } else return;
  _Float16 hi = (_Float16)v;               // RTN
  _Float16 lo = (_Float16)(v - (float)hi);
  W[off_hi] = hi; W[off_lo] = lo;
}

__global__ __launch_bounds__(128, 1) void ssm_kernel(
    const float* __restrict__ x, float* __restrict__ y,
    const _Float16* __restrict__ W, const float* __restrict__ Bbs) {
  const int tid = threadIdx.x;
  const int wv  = tid >> 6;      // wave 0/1
  const int l   = tid & 63;
  const int n   = l & 15;        // batch
  const int q   = l >> 4;        // lane group
  const int c   = blockIdx.x;
  const int t0  = c * LCH, te = t0 + LCH;
  const int ts  = (t0 > WTOT)  ? (t0 - WTOT)  : 0;
  const int tf  = (t0 > WFULL) ? (t0 - WFULL) : 0;

  const _Float16* Ah = W;
  const _Float16* Al = W + 16384;
  const _Float16* Bh = W + 32768;
  const _Float16* Bl = W + 40960;
  const _Float16* Ch = W + 49152;
  const _Float16* Cl = W + 57344;

  // ---- per-wave weights (m = 4*wv + i for recurrence, mo = 2*wv + j for emit)
  v8h afh[4][4], afl[4][4], bwh[4][2], bwl[4][2], cwh[2][4], cwl[2][4];
  v4f bb[4];
#pragma unroll
  for (int i = 0; i < 4; ++i) {
    int row = 16 * (4 * wv + i) + n;
#pragma unroll
    for (int kt = 0; kt < 4; ++kt) {
      afh[i][kt] = *(const v8h*)(Ah + row * 128 + 32 * kt + 8 * q);
      afl[i][kt] = *(const v8h*)(Al + row * 128 + 32 * kt + 8 * q);
    }
#pragma unroll
    for (int k2 = 0; k2 < 2; ++k2) {
      bwh[i][k2] = *(const v8h*)(Bh + row * 64 + 32 * k2 + 8 * q);
      bwl[i][k2] = *(const v8h*)(Bl + row * 64 + 32 * k2 + 8 * q);
    }
    bb[i] = *(const v4f*)(Bbs + 16 * (4 * wv + i) + 4 * q);
  }
#pragma unroll
  for (int j = 0; j < 2; ++j) {
    int row = 16 * (2 * wv + j) + n;
#pragma unroll
    for (int kt = 0; kt < 4; ++kt) {
      cwh[j][kt] = *(const v8h*)(Ch + row * 128 + 32 * kt + 8 * q);
      cwl[j][kt] = *(const v8h*)(Cl + row * 128 + 32 * kt + 8 * q);
    }
  }

  __shared__ _Float16 hxch[2][2][4][512];  // [parity][hi/lo][kt][lane*8]

  const float* xb = x + (size_t)n * (SEQ * DIN) + 8 * q;
  float* yb = y + (size_t)n * (SEQ * DIN);

  v4f bufA[4], bufB[4];
  auto loadx = [&](v4f(&buf)[4], int t) {
    const float* p = xb + (size_t)t * DIN;
    buf[0] = *(const v4f*)(p);
    buf[1] = *(const v4f*)(p + 4);
    buf[2] = *(const v4f*)(p + 32);
    buf[3] = *(const v4f*)(p + 36);
  };
  loadx(bufA, ts);
  loadx(bufB, ts + 1);

  v8h hf[4], hlo[4];
#pragma unroll
  for (int kt = 0; kt < 4; ++kt) { hf[kt] = v8h{}; hlo[kt] = v8h{}; }

  auto emit_y = [&](int t) {
#pragma unroll
    for (int j = 0; j < 2; ++j) {
      v4f e1 = {0.f,0.f,0.f,0.f}, e2 = {0.f,0.f,0.f,0.f}, e3 = {0.f,0.f,0.f,0.f};
#pragma unroll
      for (int kt = 0; kt < 4; ++kt) e1 = MFMA(cwh[j][kt], hf[kt],  e1);
#pragma unroll
      for (int kt = 0; kt < 4; ++kt) e2 = MFMA(cwh[j][kt], hlo[kt], e2);
#pragma unroll
      for (int kt = 0; kt < 4; ++kt) e3 = MFMA(cwl[j][kt], hf[kt],  e3);
      v4f r = e1 + e2 + e3;
      *(v4f*)(yb + (size_t)t * DIN + 16 * (2 * wv + j) + 4 * q) = r;
    }
  };

  // 16 f32 -> hi frags (RTZ; lo compensates) + lo frags
  auto split_x = [&](const v4f(&b)[4], v8h& xh0, v8h& xh1, v8h& xl0, v8h& xl1) {
    union { v2h h2[4]; v8h h8; } H0, H1, L0, L1;
    H0.h2[0] = PKRTZ(b[0][0], b[0][1]); H0.h2[1] = PKRTZ(b[0][2], b[0][3]);
    H0.h2[2] = PKRTZ(b[1][0], b[1][1]); H0.h2[3] = PKRTZ(b[1][2], b[1][3]);
    H1.h2[0] = PKRTZ(b[2][0], b[2][1]); H1.h2[1] = PKRTZ(b[2][2], b[2][3]);
    H1.h2[2] = PKRTZ(b[3][0], b[3][1]); H1.h2[3] = PKRTZ(b[3][2], b[3][3]);
    float r[16];
#pragma unroll
    for (int i = 0; i < 8; ++i) r[i]     = b[i >> 2][i & 3]       - (float)H0.h8[i];
#pragma unroll
    for (int i = 0; i < 8; ++i) r[8 + i] = b[2 + (i >> 2)][i & 3] - (float)H1.h8[i];
    L0.h2[0] = PKRTZ(r[0], r[1]);   L0.h2[1] = PKRTZ(r[2], r[3]);
    L0.h2[2] = PKRTZ(r[4], r[5]);   L0.h2[3] = PKRTZ(r[6], r[7]);
    L1.h2[0] = PKRTZ(r[8], r[9]);   L1.h2[1] = PKRTZ(r[10], r[11]);
    L1.h2[2] = PKRTZ(r[12], r[13]); L1.h2[3] = PKRTZ(r[14], r[15]);
    xh0 = H0.h8; xh1 = H1.h8; xl0 = L0.h8; xl1 = L1.h8;
  };

  // write this wave's D pieces: dwords {wv, wv+2} of each lane's slot
  auto xchg_write = [&](int pr, const v4f(&acc)[4], bool full) {
#pragma unroll
    for (int kt = 0; kt < 4; ++kt) {
      v2h hi0 = PKRTZ(acc[kt][0], acc[kt][1]);
      v2h hi1 = PKRTZ(acc[kt][2], acc[kt][3]);
      v2h* slotH = (v2h*)&hxch[pr][0][kt][l * 8];
      slotH[wv]     = hi0;
      slotH[wv + 2] = hi1;
      if (full) {
        float r0 = acc[kt][0] - (float)hi0[0];
        float r1 = acc[kt][1] - (float)hi0[1];
        float r2 = acc[kt][2] - (float)hi1[0];
        float r3 = acc[kt][3] - (float)hi1[1];
        v2h* slotL = (v2h*)&hxch[pr][1][kt][l * 8];
        slotL[wv]     = PKRTZ(r0, r1);
        slotL[wv + 2] = PKRTZ(r2, r3);
      }
    }
  };

  auto step_full = [&](int t, v4f(&buf)[4], int pr, bool emit) {
    if (emit) emit_y(t - 1);
    v8h xh0, xh1, xl0, xl1;
    split_x(buf, xh0, xh1, xl0, xl1);
    int tn = t + 2; if (tn > SEQ - 1) tn = SEQ - 1;
    loadx(buf, tn);
    v4f acc[4];
#pragma unroll
    for (int i = 0; i < 4; ++i) {
      v4f c1 = bb[i], c2 = {0.f,0.f,0.f,0.f}, c3 = {0.f,0.f,0.f,0.f};
      c1 = MFMA(bwh[i][0], xh0, c1); c1 = MFMA(bwh[i][1], xh1, c1);
      c2 = MFMA(bwl[i][0], xh0, c2); c2 = MFMA(bwl[i][1], xh1, c2);
      c3 = MFMA(bwh[i][0], xl0, c3); c3 = MFMA(bwh[i][1], xl1, c3);
#pragma unroll
      for (int kt = 0; kt < 4; ++kt) {
        c1 = MFMA(afh[i][kt], hf[kt],  c1);   // A_hi h_hi (+u_hi)
        c2 = MFMA(afl[i][kt], hf[kt],  c2);   // A_lo h_hi
        c3 = MFMA(afh[i][kt], hlo[kt], c3);   // A_hi h_lo
      }
      acc[i] = c1 + c2 + c3;
    }
    xchg_write(pr, acc, true);
    __syncthreads();
#pragma unroll
    for (int kt = 0; kt < 4; ++kt) {
      hf[kt]  = *(const v8h*)&hxch[pr][0][kt][l * 8];
      hlo[kt] = *(const v8h*)&hxch[pr][1][kt][l * 8];
    }
  };

  auto step_cheap = [&](int t, v4f(&buf)[4], int pr) {
    v8h xh0, xh1;
    {
      union { v2h h2[4]; v8h h8; } H0, H1;
      H0.h2[0] = PKRTZ(buf[0][0], buf[0][1]); H0.h2[1] = PKRTZ(buf[0][2], buf[0][3]);
      H0.h2[2] = PKRTZ(buf[1][0], buf[1][1]); H0.h2[3] = PKRTZ(buf[1][2], buf[1][3]);
      H1.h2[0] = PKRTZ(buf[2][0], buf[2][1]); H1.h2[1] = PKRTZ(buf[2][2], buf[2][3]);
      H1.h2[2] = PKRTZ(buf[3][0], buf[3][1]); H1.h2[3] = PKRTZ(buf[3][2], buf[3][3]);
      xh0 = H0.h8; xh1 = H1.h8;
    }
    int tn = t + 2; if (tn > SEQ - 1) tn = SEQ - 1;
    loadx(buf, tn);
    v4f acc[4];
#pragma unroll
    for (int i = 0; i < 4; ++i) {
      v4f c1 = bb[i];
      c1 = MFMA(bwh[i][0], xh0, c1); c1 = MFMA(bwh[i][1], xh1, c1);
#pragma unroll
      for (int kt = 0; kt < 4; ++kt) c1 = MFMA(afh[i][kt], hf[kt], c1);
      acc[i] = c1;
    }
    xchg_write(pr, acc, false);
    __syncthreads();
#pragma unroll
    for (int kt = 0; kt < 4; ++kt) hf[kt] = *(const v8h*)&hxch[pr][0][kt][l * 8];
  };

  // all phase lengths are even for every chunk (0/16/32/48/64 cheap, 0/32/48 warm, 32 out)
  for (int t = ts; t < tf; t += 2) { step_cheap(t, bufA, 0); step_cheap(t + 1, bufB, 1); }
  for (int t = tf; t < t0; t += 2) { step_full(t, bufA, 0, false); step_full(t + 1, bufB, 1, false); }
  for (int t = t0; t < te; t += 2) { step_full(t, bufA, 0, t > t0); step_full(t + 1, bufB, 1, true); }
  emit_y(te - 1);
}

extern "C" void kernel_launch(void* const* d_in, const int* in_sizes, int n_in,
                              void* d_out, int out_size, void* d_ws, size_t ws_size,
                              hipStream_t stream) {
  const float* x  = (const float*)d_in[0];
  const float* A  = (const float*)d_in[1];
  const float* Bw = (const float*)d_in[2];
  const float* Bb = (const float*)d_in[3];
  const float* Cw = (const float*)d_in[4];
  float* y = (float*)d_out;

  _Float16* W   = (_Float16*)d_ws;
  float*    Bbs = (float*)(W + 65536);     // needs 131584 B of ws

  prep_kernel<<<129, 256, 0, stream>>>(A, Bw, Bb, Cw, W, Bbs);
  ssm_kernel<<<NCH, 128, 0, stream>>>(x, y, W, Bbs);
}

// Round 4
// 102.343 us; speedup vs baseline: 1.2898x; 1.2898x over previous
//
#include <hip/hip_runtime.h>

// StructuredStateSpace: h_t = A h_{t-1} + Bw x_t + Bb ; y_t = Cw h_t
// B=16, S=8192, D_IN=64, D_ST=128.  Output scale +-488, threshold 0.32 =>
// ~6.6e-4 relative accuracy: A/Bw/Cw/h all carried as f16 hi+lo pairs,
// products keep 3 of 4 cross terms (validated round 3: absmax 0.156).
//
// Round-4 structure: 4-wave m-split (wave w owns D-tiles m in {w, w+4}, which
// by the rho permutation produce the COMPLETE next-state B-fragment kt=w ->
// per-step exchange is one ds_write_b128 hi + one lo, conflict-free), plus
// u-pipelining (u_t = Bb + Bw x_t built one step ahead, off the h critical
// path -> recurrence chain is exactly 4 MFMAs deep).

#define SEQ   8192
#define DIN   64
#define LCH   32
#define NCH   (SEQ / LCH)        // 256 blocks = 1 per CU
#define WFULL 48
#define WTOT  112

typedef _Float16 v8h __attribute__((ext_vector_type(8)));
typedef __fp16   v2h __attribute__((ext_vector_type(2)));
typedef float    v4f __attribute__((ext_vector_type(4)));

#define MFMA(a, b, c) __builtin_amdgcn_mfma_f32_16x16x32_f16((a), (b), (c), 0, 0, 0)
#define PKRTZ __builtin_amdgcn_cvt_pkrtz

// rho: logical state l = 32*kt + 8*q + e  ->  physical D-row p = 16*m + 4*q + r
// with m = kt + 4*(eh&1), r = 2*(eh>>1) + (e&1), eh = e>>1.
__device__ __forceinline__ int rho_inv(int p) {
  int m = p >> 4, q = (p >> 2) & 3, r = p & 3;
  int eh = ((r >> 1) << 1) | (m >> 2);
  int e  = (eh << 1) | (r & 1);
  return 32 * (m & 3) + 8 * q + e;
}

// ws (f16 units): Ah[0,16384) Al[16384,32768) Bwh[32768,40960) Bwl[40960,49152)
// Cwh[49152,57344) Cwl[57344,65536) ; then f32 Bb[128].  Total 131584 B.
__global__ void prep_kernel(const float* __restrict__ A, const float* __restrict__ Bw,
                            const float* __restrict__ Bb, const float* __restrict__ Cw,
                            _Float16* __restrict__ W, float* __restrict__ Bbs) {
  int idx = blockIdx.x * 256 + threadIdx.x;
  float v; int off_hi, off_lo;
  if (idx < 16384) {                       // A: 128x128, rho rows
    int p = idx >> 7, j = idx & 127;
    v = A[rho_inv(p) * 128 + j]; off_hi = idx; off_lo = idx + 16384;
  } else if (idx < 24576) {                // Bw: 128x64, rho rows
    int i2 = idx - 16384; int p = i2 >> 6, j = i2 & 63;
    v = Bw[rho_inv(p) * 64 + j]; off_hi = 32768 + i2; off_lo = 40960 + i2;
  } else if (idx < 32768) {                // Cw: 64x128, plain
    int i2 = idx - 24576;
    v = Cw[i2]; off_hi = 49152 + i2; off_lo = 57344 + i2;
  } else if (idx < 32896) {                // Bb f32, rho
    Bbs[idx - 32768] = Bb[rho_inv(idx - 32768)]; return;
  } else return;
  _Float16 hi = (_Float16)v;
  _Float16 lo = (_Float16)(v - (float)hi);
  W[off_hi] = hi; W[off_lo] = lo;
}

__global__ __launch_bounds__(256, 1) void ssm_kernel(
    const float* __restrict__ x, float* __restrict__ y,
    const _Float16* __restrict__ W, const float* __restrict__ Bbs) {
  const int tid = threadIdx.x;
  const int wv  = tid >> 6;      // wave 0..3: owns m in {wv, wv+4}; emits tile wv
  const int l   = tid & 63;
  const int n   = l & 15;        // batch
  const int q   = l >> 4;        // lane group
  const int c   = blockIdx.x;
  const int t0  = c * LCH, te = t0 + LCH;
  const int ts  = (t0 > WTOT)  ? (t0 - WTOT)  : 0;
  const int tf  = (t0 > WFULL) ? (t0 - WFULL) : 0;

  const _Float16* Ah = W;
  const _Float16* Al = W + 16384;
  const _Float16* Bh = W + 32768;
  const _Float16* Bl = W + 40960;
  const _Float16* Ch = W + 49152;
  const _Float16* Cl = W + 57344;

  // ---- per-wave weights: i in {0,1} -> m_i = wv + 4*i
  v8h afh[2][4], afl[2][4], bwh[2][2], bwl[2][2], cwh[4], cwl[4];
  v4f bb2[2];
#pragma unroll
  for (int i = 0; i < 2; ++i) {
    int row = 16 * (wv + 4 * i) + n;
#pragma unroll
    for (int kt = 0; kt < 4; ++kt) {
      afh[i][kt] = *(const v8h*)(Ah + row * 128 + 32 * kt + 8 * q);
      afl[i][kt] = *(const v8h*)(Al + row * 128 + 32 * kt + 8 * q);
    }
#pragma unroll
    for (int k2 = 0; k2 < 2; ++k2) {
      bwh[i][k2] = *(const v8h*)(Bh + row * 64 + 32 * k2 + 8 * q);
      bwl[i][k2] = *(const v8h*)(Bl + row * 64 + 32 * k2 + 8 * q);
    }
    bb2[i] = *(const v4f*)(Bbs + 16 * (wv + 4 * i) + 4 * q);
  }
  {
    int row = 16 * wv + n;
#pragma unroll
    for (int kt = 0; kt < 4; ++kt) {
      cwh[kt] = *(const v8h*)(Ch + row * 128 + 32 * kt + 8 * q);
      cwl[kt] = *(const v8h*)(Cl + row * 128 + 32 * kt + 8 * q);
    }
  }

  __shared__ _Float16 hx[2][2][4][512];   // [parity][hi/lo][kt][lane*8]

  const float* xb = x + (size_t)n * (SEQ * DIN) + 8 * q;
  float* yb = y + (size_t)n * (SEQ * DIN);

  v4f bufA[4], bufB[4];                   // x double buffer (even / odd t+1)
  auto loadx = [&](v4f(&buf)[4], int t) {
    const float* p = xb + (size_t)t * DIN;
    buf[0] = *(const v4f*)(p);
    buf[1] = *(const v4f*)(p + 4);
    buf[2] = *(const v4f*)(p + 32);
    buf[3] = *(const v4f*)(p + 36);
  };

  v8h hf[4], hlo[4];
#pragma unroll
  for (int kt = 0; kt < 4; ++kt) { hf[kt] = v8h{}; hlo[kt] = v8h{}; }

  v4f uA[2], uB[2];                       // u_t = Bb + Bw x_t (hi path / corrections)

  // build u for the step that will consume buffer b; full => include lo terms
  auto build_u = [&](const v4f(&b)[4], bool full) {
    union { v2h h2[4]; v8h h8; } H0, H1;
    H0.h2[0] = PKRTZ(b[0][0], b[0][1]); H0.h2[1] = PKRTZ(b[0][2], b[0][3]);
    H0.h2[2] = PKRTZ(b[1][0], b[1][1]); H0.h2[3] = PKRTZ(b[1][2], b[1][3]);
    H1.h2[0] = PKRTZ(b[2][0], b[2][1]); H1.h2[1] = PKRTZ(b[2][2], b[2][3]);
    H1.h2[2] = PKRTZ(b[3][0], b[3][1]); H1.h2[3] = PKRTZ(b[3][2], b[3][3]);
    v8h xh0 = H0.h8, xh1 = H1.h8;
#pragma unroll
    for (int i = 0; i < 2; ++i) {
      v4f a = bb2[i];
      a = MFMA(bwh[i][0], xh0, a);
      a = MFMA(bwh[i][1], xh1, a);
      uA[i] = a;
    }
    if (full) {
      float r[16];
#pragma unroll
      for (int i = 0; i < 8; ++i) r[i]     = b[i >> 2][i & 3]       - (float)H0.h8[i];
#pragma unroll
      for (int i = 0; i < 8; ++i) r[8 + i] = b[2 + (i >> 2)][i & 3] - (float)H1.h8[i];
      union { v2h h2[4]; v8h h8; } L0, L1;
      L0.h2[0] = PKRTZ(r[0], r[1]);   L0.h2[1] = PKRTZ(r[2], r[3]);
      L0.h2[2] = PKRTZ(r[4], r[5]);   L0.h2[3] = PKRTZ(r[6], r[7]);
      L1.h2[0] = PKRTZ(r[8], r[9]);   L1.h2[1] = PKRTZ(r[10], r[11]);
      L1.h2[2] = PKRTZ(r[12], r[13]); L1.h2[3] = PKRTZ(r[14], r[15]);
      v8h xl0 = L0.h8, xl1 = L1.h8;
#pragma unroll
      for (int i = 0; i < 2; ++i) {
        v4f a = {0.f, 0.f, 0.f, 0.f};
        a = MFMA(bwl[i][0], xh0, a);
        a = MFMA(bwl[i][1], xh1, a);
        a = MFMA(bwh[i][0], xl0, a);
        a = MFMA(bwh[i][1], xl1, a);
        uB[i] = a;
      }
    }
  };

  auto emit_y = [&](int t) {
    v4f e1 = {0.f,0.f,0.f,0.f}, e2 = {0.f,0.f,0.f,0.f}, e3 = {0.f,0.f,0.f,0.f};
#pragma unroll
    for (int kt = 0; kt < 4; ++kt) e1 = MFMA(cwh[kt], hf[kt],  e1);
#pragma unroll
    for (int kt = 0; kt < 4; ++kt) e2 = MFMA(cwh[kt], hlo[kt], e2);
#pragma unroll
    for (int kt = 0; kt < 4; ++kt) e3 = MFMA(cwl[kt], hf[kt],  e3);
    v4f r = e1 + e2 + e3;
    *(v4f*)(yb + (size_t)t * DIN + 16 * wv + 4 * q) = r;
  };

  // pack this wave's two D-tiles into B-frag kt=wv and write to LDS
  auto xwrite = [&](int pr, const v4f& a0, const v4f& a1, bool full) {
    union { v2h h2[4]; v8h h8; } U;
    U.h2[0] = PKRTZ(a0[0], a0[1]); U.h2[1] = PKRTZ(a1[0], a1[1]);
    U.h2[2] = PKRTZ(a0[2], a0[3]); U.h2[3] = PKRTZ(a1[2], a1[3]);
    *(v8h*)&hx[pr][0][wv][l * 8] = U.h8;
    if (full) {
      float r0 = a0[0] - (float)U.h8[0], r1 = a0[1] - (float)U.h8[1];
      float r2 = a1[0] - (float)U.h8[2], r3 = a1[1] - (float)U.h8[3];
      float r4 = a0[2] - (float)U.h8[4], r5 = a0[3] - (float)U.h8[5];
      float r6 = a1[2] - (float)U.h8[6], r7 = a1[3] - (float)U.h8[7];
      union { v2h h2[4]; v8h h8; } L;
      L.h2[0] = PKRTZ(r0, r1); L.h2[1] = PKRTZ(r2, r3);
      L.h2[2] = PKRTZ(r4, r5); L.h2[3] = PKRTZ(r6, r7);
      *(v8h*)&hx[pr][1][wv][l * 8] = L.h8;
    }
  };

  // even t: u-src = bufB (x_{t+1}), reload bufA <- x_{t+2}, pr=0; odd t: swapped
  auto step_full = [&](int t, v4f(&bsrc)[4], v4f(&bld)[4], int pr, bool emit) {
    if (emit) emit_y(t - 1);
    v4f c1[2], c2[2], c3[2];
#pragma unroll
    for (int i = 0; i < 2; ++i) {
      c1[i] = uA[i]; c2[i] = uB[i]; c3[i] = v4f{0.f, 0.f, 0.f, 0.f};
    }
#pragma unroll
    for (int kt = 0; kt < 4; ++kt)
#pragma unroll
      for (int i = 0; i < 2; ++i) {
        c1[i] = MFMA(afh[i][kt], hf[kt],  c1[i]);
        c2[i] = MFMA(afl[i][kt], hf[kt],  c2[i]);
        c3[i] = MFMA(afh[i][kt], hlo[kt], c3[i]);
      }
    build_u(bsrc, true);                 // u_{t+1}, off critical path
    int tn = t + 2; if (tn > SEQ - 1) tn = SEQ - 1;
    loadx(bld, tn);
    v4f a0 = c1[0] + c2[0] + c3[0];
    v4f a1 = c1[1] + c2[1] + c3[1];
    xwrite(pr, a0, a1, true);
    __syncthreads();
#pragma unroll
    for (int kt = 0; kt < 4; ++kt) {
      hf[kt]  = *(const v8h*)&hx[pr][0][kt][l * 8];
      hlo[kt] = *(const v8h*)&hx[pr][1][kt][l * 8];
    }
  };

  auto step_cheap = [&](int t, v4f(&bsrc)[4], v4f(&bld)[4], int pr) {
    v4f c1[2];
#pragma unroll
    for (int i = 0; i < 2; ++i) c1[i] = uA[i];
#pragma unroll
    for (int kt = 0; kt < 4; ++kt)
#pragma unroll
      for (int i = 0; i < 2; ++i) c1[i] = MFMA(afh[i][kt], hf[kt], c1[i]);
    build_u(bsrc, (t + 1) >= tf);
    loadx(bld, t + 2);                   // cheap phase: t+2 < t0 < SEQ
    xwrite(pr, c1[0], c1[1], false);
    __syncthreads();
#pragma unroll
    for (int kt = 0; kt < 4; ++kt) hf[kt] = *(const v8h*)&hx[pr][0][kt][l * 8];
  };

  loadx(bufA, ts);
  loadx(bufB, ts + 1);
  build_u(bufA, ts >= tf);               // u for first step

  // all phase boundaries are even -> clean even/odd pairs
  for (int t = ts; t < tf; t += 2) {
    step_cheap(t,     bufB, bufA, 0);
    step_cheap(t + 1, bufA, bufB, 1);
  }
  for (int t = tf; t < t0; t += 2) {
    step_full(t,     bufB, bufA, 0, false);
    step_full(t + 1, bufA, bufB, 1, false);
  }
  for (int t = t0; t < te; t += 2) {
    step_full(t,     bufB, bufA, 0, t > t0);
    step_full(t + 1, bufA, bufB, 1, true);
  }
  emit_y(te - 1);
}

extern "C" void kernel_launch(void* const* d_in, const int* in_sizes, int n_in,
                              void* d_out, int out_size, void* d_ws, size_t ws_size,
                              hipStream_t stream) {
  const float* x  = (const float*)d_in[0];
  const float* A  = (const float*)d_in[1];
  const float* Bw = (const float*)d_in[2];
  const float* Bb = (const float*)d_in[3];
  const float* Cw = (const float*)d_in[4];
  float* y = (float*)d_out;

  _Float16* W   = (_Float16*)d_ws;
  float*    Bbs = (float*)(W + 65536);   // needs 131584 B of ws

  prep_kernel<<<129, 256, 0, stream>>>(A, Bw, Bb, Cw, W, Bbs);
  ssm_kernel<<<NCH, 256, 0, stream>>>(x, y, W, Bbs);
}